// Round 6
// baseline (95.630 us; speedup 1.0000x reference)
//
#include <hip/hip_runtime.h>
#include <math.h>

// Fixed problem shape: B=8, N=M=4096, 3-D f32 points.
#define NPTS   4096
#define NB     8
#define TPB    1024
#define QB     512            // queries per block -> 8 per thread
#define CHUNK  1024           // candidates per block (quarter cloud)
#define SEGS   16             // one wave per segment
#define CPS    (CHUNK / SEGS) // 64 candidates per segment = 1 b128/lane
#define NCHUNK 4
#define GRID1  512            // 2 dirs * 8 batches * 8 qblks * 4 chunks
#define NQTOT  65536          // 2 * 8 * 4096 queries

// monotone float->uint mapping (total order == float order, handles negatives)
__device__ __forceinline__ unsigned f2mono(float f) {
    unsigned b = __float_as_uint(f);
    unsigned mask = (unsigned)(((int)b) >> 31) | 0x80000000u;
    return b ^ mask;
}
__device__ __forceinline__ float mono2f(unsigned u) {
    unsigned mask = (u >> 31) ? 0x80000000u : 0xFFFFFFFFu;
    return __uint_as_float(u ^ mask);
}

// ws layout: u64 res[NCHUNK][NQTOT] packed (mono(dist)<<32)|idx, plain stores.

// Kernel 1: value-only min3 scan (8 queries/thread for LDS-read reuse),
// exact argmin recovery via single-b128 segment rescan + ballot.
__global__ __launch_bounds__(TPB, 8) void chamfer6_scan(
    const float* __restrict__ xyz1, const float* __restrict__ xyz2,
    unsigned long long* __restrict__ res, float* __restrict__ out)
{
    __shared__ float4 sc[CHUNK];                   // 16 KB (x,y,z,|r|^2)
    __shared__ float  sBest[SEGS * QB];            // 32 KB
    __shared__ float  qMin[QB];                    // 2 KB
    __shared__ int    qSeg[QB];                    // 2 KB
    __shared__ float4 qM[QB];                      // 8 KB (-2q, |q|^2)
    __shared__ unsigned long long qPk[QB];         // 4 KB  (total 64 KB)

    int bid   = blockIdx.x;
    int dir   = bid >> 8;
    int b     = (bid >> 5) & 7;
    int qblk  = (bid >> 2) & 7;
    int chunk = bid & 3;

    int tid  = threadIdx.x;
    int lane = tid & 63;
    int wid  = tid >> 6;

    if (bid == 0 && tid == 0) { out[0] = 0.f; out[1] = 0.f; }  // out poisoned 0xAA

    const float* qb = (dir ? xyz2 : xyz1) + (size_t)b * NPTS * 3;
    const float* rb = (dir ? xyz1 : xyz2) + ((size_t)b * NPTS + chunk * CHUNK) * 3;

    // ---- stage CHUNK candidates as (x,y,z,r^2): 256 threads x 4 points ----
    if (tid < CHUNK / 4) {
        const float4* rb4 = (const float4*)rb;     // 12 KB, 16B-aligned
        float4 v0 = rb4[tid * 3 + 0];
        float4 v1 = rb4[tid * 3 + 1];
        float4 v2 = rb4[tid * 3 + 2];
        int p = tid * 4;
        sc[p + 0] = make_float4(v0.x, v0.y, v0.z, fmaf(v0.x, v0.x, fmaf(v0.y, v0.y, v0.z * v0.z)));
        sc[p + 1] = make_float4(v0.w, v1.x, v1.y, fmaf(v0.w, v0.w, fmaf(v1.x, v1.x, v1.y * v1.y)));
        sc[p + 2] = make_float4(v1.z, v1.w, v2.x, fmaf(v1.z, v1.z, fmaf(v1.w, v1.w, v2.x * v2.x)));
        sc[p + 3] = make_float4(v2.y, v2.z, v2.w, fmaf(v2.y, v2.y, fmaf(v2.z, v2.z, v2.w * v2.w)));
    }
    // ---- per-query (-2q, |q|^2), shared by scan and rescan (bit-identical) ----
    if (tid < QB) {
        const float* p = qb + (qblk * QB + tid) * 3;
        float qx = p[0], qy = p[1], qz = p[2];
        qM[tid] = make_float4(-2.f * qx, -2.f * qy, -2.f * qz,
                              fmaf(qx, qx, fmaf(qy, qy, qz * qz)));
    }
    __syncthreads();

    // ---- registers for my 8 queries ----
    float mx[8], my[8], mz[8], bE[8];
    #pragma unroll
    for (int u = 0; u < 8; ++u) {
        float4 m = qM[u * 64 + lane];
        mx[u] = m.x; my[u] = m.y; mz[u] = m.z;
        bE[u] = INFINITY;
    }

    // ---- value-only scan: 64-candidate segment, 8 queries/thread ----
    int jb = wid * CPS;
    #pragma unroll 2
    for (int jo = 0; jo < CPS; jo += 4) {
        float4 c0 = sc[jb + jo + 0];   // broadcast reads (wave-uniform addr)
        float4 c1 = sc[jb + jo + 1];
        float4 c2 = sc[jb + jo + 2];
        float4 c3 = sc[jb + jo + 3];
        #pragma unroll
        for (int u = 0; u < 8; ++u) {
            float d0 = fmaf(mx[u], c0.x, fmaf(my[u], c0.y, fmaf(mz[u], c0.z, c0.w)));
            float d1 = fmaf(mx[u], c1.x, fmaf(my[u], c1.y, fmaf(mz[u], c1.z, c1.w)));
            float d2 = fmaf(mx[u], c2.x, fmaf(my[u], c2.y, fmaf(mz[u], c2.z, c2.w)));
            float d3 = fmaf(mx[u], c3.x, fmaf(my[u], c3.y, fmaf(mz[u], c3.z, c3.w)));
            bE[u] = fminf(fminf(bE[u], d0), d1);   // -> v_min3_f32
            bE[u] = fminf(fminf(bE[u], d2), d3);
        }
    }
    #pragma unroll
    for (int u = 0; u < 8; ++u)
        sBest[wid * QB + u * 64 + lane] = bE[u];
    __syncthreads();

    // ---- combine across segments (value + first winning segment) ----
    if (tid < QB) {
        float best = sBest[tid]; int bs = 0;
        #pragma unroll
        for (int s = 1; s < SEGS; ++s) {
            float v = sBest[s * QB + tid];
            if (v < best) { best = v; bs = s; }   // strict <: lowest seg on tie
        }
        qMin[tid] = best; qSeg[tid] = bs;
    }
    __syncthreads();

    // ---- rescan winning 64-cand segment: exact FMA replay + ballot-ffs ----
    #pragma unroll 4
    for (int k = 0; k < QB / SEGS; ++k) {          // 32 queries per wave
        int q = wid * (QB / SEGS) + k;
        float minv = qMin[q];
        int   seg  = qSeg[q];
        float4 m   = qM[q];
        float4 ca  = sc[seg * CPS + lane];
        float da = fmaf(m.x, ca.x, fmaf(m.y, ca.y, fmaf(m.z, ca.z, ca.w)));
        unsigned long long ba = __ballot(da == minv);
        if (lane == 0) {
            int off  = __ffsll(ba) - 1;
            int gidx = chunk * CHUNK + seg * CPS + off;   // 0..4095
            float dist = minv + m.w;                      // |q|^2 + (r^2 - 2qr)
            qPk[q] = ((unsigned long long)f2mono(dist) << 32) | (unsigned)gidx;
        }
    }
    __syncthreads();

    // ---- coalesced store of 512 packed results ----
    if (tid < QB) {
        unsigned qglob = (unsigned)(dir * (NB * NPTS) + b * NPTS + qblk * QB + tid);
        res[(size_t)chunk * NQTOT + qglob] = qPk[tid];
    }
}

// Kernel 2: combine chunks (u64 min == first-min on (dist,idx)), normal term,
// block partial sums -> 2 atomicAdds into out (zeroed by kernel 1).
__global__ __launch_bounds__(256) void chamfer6_finalize(
    const float* __restrict__ nrm1, const float* __restrict__ nrm2,
    const unsigned long long* __restrict__ res, float* __restrict__ out)
{
    __shared__ float fin[8];
    int tid = threadIdx.x;
    int gq  = blockIdx.x * 256 + tid;

    unsigned long long pk = res[gq];
    #pragma unroll
    for (int c = 1; c < NCHUNK; ++c) {
        unsigned long long p2 = res[(size_t)c * NQTOT + gq];
        pk = p2 < pk ? p2 : pk;
    }
    float dist = mono2f((unsigned)(pk >> 32));
    int   idx  = (int)(pk & 0xFFFFFFFFu);          // 0..4095

    int d2  = gq >> 15;            // direction
    int rem = gq & 32767;          // b*4096 + n
    int bb  = rem >> 12;           // batch

    const float* a3 = (d2 ? nrm2 : nrm1) + (size_t)rem * 3;
    const float* t3 = (d2 ? nrm1 : nrm2) + ((size_t)bb * NPTS + idx) * 3;
    float ax = a3[0], ay = a3[1], az = a3[2];
    float ia = 1.f / fmaxf(sqrtf(fmaf(ax, ax, fmaf(ay, ay, az * az))), 1e-12f);
    ax *= ia; ay *= ia; az *= ia;
    float bx = t3[0], by = t3[1], bz = t3[2];
    float ib = 1.f / fmaxf(sqrtf(fmaf(bx, bx, fmaf(by, by, bz * bz))), 1e-12f);
    bx *= ib; by *= ib; bz *= ib;
    float ex = ax - bx, ey = ay - by, ez = az - bz;
    float px = ax + bx, py = ay + by, pz = az + bz;
    float dm = fmaf(ex, ex, fmaf(ey, ey, ez * ez));
    float dp = fmaf(px, px, fmaf(py, py, pz * pz));
    float nd = fminf(dm, dp);

    for (int off = 32; off > 0; off >>= 1) {
        dist += __shfl_down(dist, off, 64);
        nd   += __shfl_down(nd,   off, 64);
    }
    int wave = tid >> 6, lane = tid & 63;
    if (lane == 0) { fin[wave * 2] = dist; fin[wave * 2 + 1] = nd; }
    __syncthreads();
    if (tid == 0) {
        const float inv = 1.0f / 32768.0f;
        float a = (fin[0] + fin[2] + fin[4] + fin[6]) * inv;
        float c = (fin[1] + fin[3] + fin[5] + fin[7]) * inv;
        atomicAdd(&out[0], a);   // loss_xyz
        atomicAdd(&out[1], c);   // loss_normal
    }
}

extern "C" void kernel_launch(void* const* d_in, const int* in_sizes, int n_in,
                              void* d_out, int out_size, void* d_ws, size_t ws_size,
                              hipStream_t stream) {
    const float* xyz1 = (const float*)d_in[0];   // [8,4096,3]
    const float* xyz2 = (const float*)d_in[1];
    const float* nrm1 = (const float*)d_in[2];   // normal_rebuild
    const float* nrm2 = (const float*)d_in[3];   // normal_gt
    float* out = (float*)d_out;

    unsigned long long* res = (unsigned long long*)d_ws;   // 2 MB

    chamfer6_scan<<<GRID1, TPB, 0, stream>>>(xyz1, xyz2, res, out);
    chamfer6_finalize<<<NQTOT / 256, 256, 0, stream>>>(nrm1, nrm2, res, out);
}

// Round 7
// 95.082 us; speedup vs baseline: 1.0058x; 1.0058x over previous
//
#include <hip/hip_runtime.h>
#include <math.h>

// Fixed problem shape: B=8, N=M=4096, 3-D f32 points.
#define NPTS   4096
#define NB     8
#define TPB    1024
#define QB     512            // queries per block -> 8 per thread
#define CHUNK  1024           // candidates per block (quarter cloud)
#define SEGS   16             // one wave per segment
#define CPS    (CHUNK / SEGS) // 64 candidates per segment
#define NCHUNK 4
#define GRID1  512            // 2 dirs * 8 batches * 8 qblks * 4 chunks
#define NQTOT  65536          // 2 * 8 * 4096 queries

// monotone float->uint mapping (total order == float order, handles negatives)
__device__ __forceinline__ unsigned f2mono(float f) {
    unsigned b = __float_as_uint(f);
    unsigned mask = (unsigned)(((int)b) >> 31) | 0x80000000u;
    return b ^ mask;
}
__device__ __forceinline__ float mono2f(unsigned u) {
    unsigned mask = (u >> 31) ? 0x80000000u : 0xFFFFFFFFu;
    return __uint_as_float(u ^ mask);
}

// ws layout: u64 res[NCHUNK][NQTOT] packed (mono(dist)<<32)|idx, plain stores.

// Kernel 1: value-only min3 scan, 8 queries/thread, 2-candidate inner step
// (keeps live VGPRs ~50 so __launch_bounds__(1024,8) holds without spills).
// Exact argmin recovered by single-b128 segment rescan + ballot-ffs.
__global__ __launch_bounds__(TPB, 8) void chamfer7_scan(
    const float* __restrict__ xyz1, const float* __restrict__ xyz2,
    unsigned long long* __restrict__ res, float* __restrict__ out)
{
    __shared__ float4 sc[CHUNK];                   // 16 KB (x,y,z,|r|^2)
    __shared__ float  sBest[SEGS * QB];            // 32 KB
    __shared__ float  qMin[QB];                    // 2 KB
    __shared__ int    qSeg[QB];                    // 2 KB
    __shared__ float4 qM[QB];                      // 8 KB (-2q, |q|^2)
    __shared__ unsigned long long qPk[QB];         // 4 KB  (total 64 KB)

    int bid   = blockIdx.x;
    int dir   = bid >> 8;
    int b     = (bid >> 5) & 7;
    int qblk  = (bid >> 2) & 7;
    int chunk = bid & 3;

    int tid  = threadIdx.x;
    int lane = tid & 63;
    int wid  = tid >> 6;

    if (bid == 0 && tid == 0) { out[0] = 0.f; out[1] = 0.f; }  // out poisoned

    const float* qb = (dir ? xyz2 : xyz1) + (size_t)b * NPTS * 3;
    const float* rb = (dir ? xyz1 : xyz2) + ((size_t)b * NPTS + chunk * CHUNK) * 3;

    // ---- parallel staging: waves 0-3 stage candidates, waves 8-15 stage qM ----
    if (tid < CHUNK / 4) {
        const float4* rb4 = (const float4*)rb;     // 12 KB, 16B-aligned
        float4 v0 = rb4[tid * 3 + 0];
        float4 v1 = rb4[tid * 3 + 1];
        float4 v2 = rb4[tid * 3 + 2];
        int p = tid * 4;
        sc[p + 0] = make_float4(v0.x, v0.y, v0.z, fmaf(v0.x, v0.x, fmaf(v0.y, v0.y, v0.z * v0.z)));
        sc[p + 1] = make_float4(v0.w, v1.x, v1.y, fmaf(v0.w, v0.w, fmaf(v1.x, v1.x, v1.y * v1.y)));
        sc[p + 2] = make_float4(v1.z, v1.w, v2.x, fmaf(v1.z, v1.z, fmaf(v1.w, v1.w, v2.x * v2.x)));
        sc[p + 3] = make_float4(v2.y, v2.z, v2.w, fmaf(v2.y, v2.y, fmaf(v2.z, v2.z, v2.w * v2.w)));
    } else if (tid >= TPB - QB) {
        int i = tid - (TPB - QB);
        const float* p = qb + (qblk * QB + i) * 3;
        float qx = p[0], qy = p[1], qz = p[2];
        qM[i] = make_float4(-2.f * qx, -2.f * qy, -2.f * qz,
                            fmaf(qx, qx, fmaf(qy, qy, qz * qz)));
    }
    __syncthreads();

    // ---- registers for my 8 queries ----
    float mx[8], my[8], mz[8], bE[8];
    #pragma unroll
    for (int u = 0; u < 8; ++u) {
        float4 m = qM[u * 64 + lane];
        mx[u] = m.x; my[u] = m.y; mz[u] = m.z;
        bE[u] = INFINITY;
    }

    // ---- value-only scan: 64-cand segment, 2 candidates/step, 8 queries ----
    int jb = wid * CPS;
    #pragma unroll 2
    for (int jo = 0; jo < CPS; jo += 2) {
        float4 c0 = sc[jb + jo + 0];   // broadcast reads (wave-uniform addr)
        float4 c1 = sc[jb + jo + 1];
        #pragma unroll
        for (int u = 0; u < 8; ++u) {
            float d0 = fmaf(mx[u], c0.x, fmaf(my[u], c0.y, fmaf(mz[u], c0.z, c0.w)));
            float d1 = fmaf(mx[u], c1.x, fmaf(my[u], c1.y, fmaf(mz[u], c1.z, c1.w)));
            bE[u] = fminf(fminf(bE[u], d0), d1);   // -> v_min3_f32
        }
    }
    #pragma unroll
    for (int u = 0; u < 8; ++u)
        sBest[wid * QB + u * 64 + lane] = bE[u];
    __syncthreads();

    // ---- combine across segments (value + first winning segment) ----
    if (tid < QB) {
        float best = sBest[tid]; int bs = 0;
        #pragma unroll
        for (int s = 1; s < SEGS; ++s) {
            float v = sBest[s * QB + tid];
            if (v < best) { best = v; bs = s; }   // strict <: lowest seg on tie
        }
        qMin[tid] = best; qSeg[tid] = bs;
    }
    __syncthreads();

    // ---- rescan winning 64-cand segment: exact FMA replay + ballot-ffs ----
    #pragma unroll 4
    for (int k = 0; k < QB / SEGS; ++k) {          // 32 queries per wave
        int q = wid * (QB / SEGS) + k;
        float minv = qMin[q];
        int   seg  = qSeg[q];
        float4 m   = qM[q];
        float4 ca  = sc[seg * CPS + lane];
        float da = fmaf(m.x, ca.x, fmaf(m.y, ca.y, fmaf(m.z, ca.z, ca.w)));
        unsigned long long ba = __ballot(da == minv);
        if (lane == 0) {
            int off  = __ffsll(ba) - 1;
            int gidx = chunk * CHUNK + seg * CPS + off;   // 0..4095
            float dist = minv + m.w;                      // |q|^2 + (r^2 - 2qr)
            qPk[q] = ((unsigned long long)f2mono(dist) << 32) | (unsigned)gidx;
        }
    }
    __syncthreads();

    // ---- coalesced store of 512 packed results ----
    if (tid < QB) {
        unsigned qglob = (unsigned)(dir * (NB * NPTS) + b * NPTS + qblk * QB + tid);
        res[(size_t)chunk * NQTOT + qglob] = qPk[tid];
    }
}

// Kernel 2: combine chunks (u64 min == first-min on (dist,idx)), normal term,
// block partial sums -> 2 atomicAdds into out (zeroed by kernel 1).
__global__ __launch_bounds__(256) void chamfer7_finalize(
    const float* __restrict__ nrm1, const float* __restrict__ nrm2,
    const unsigned long long* __restrict__ res, float* __restrict__ out)
{
    __shared__ float fin[8];
    int tid = threadIdx.x;
    int gq  = blockIdx.x * 256 + tid;

    unsigned long long pk = res[gq];
    #pragma unroll
    for (int c = 1; c < NCHUNK; ++c) {
        unsigned long long p2 = res[(size_t)c * NQTOT + gq];
        pk = p2 < pk ? p2 : pk;
    }
    float dist = mono2f((unsigned)(pk >> 32));
    int   idx  = (int)(pk & 0xFFFFFFFFu);          // 0..4095

    int d2  = gq >> 15;            // direction
    int rem = gq & 32767;          // b*4096 + n
    int bb  = rem >> 12;           // batch

    const float* a3 = (d2 ? nrm2 : nrm1) + (size_t)rem * 3;
    const float* t3 = (d2 ? nrm1 : nrm2) + ((size_t)bb * NPTS + idx) * 3;
    float ax = a3[0], ay = a3[1], az = a3[2];
    float ia = 1.f / fmaxf(sqrtf(fmaf(ax, ax, fmaf(ay, ay, az * az))), 1e-12f);
    ax *= ia; ay *= ia; az *= ia;
    float bx = t3[0], by = t3[1], bz = t3[2];
    float ib = 1.f / fmaxf(sqrtf(fmaf(bx, bx, fmaf(by, by, bz * bz))), 1e-12f);
    bx *= ib; by *= ib; bz *= ib;
    float ex = ax - bx, ey = ay - by, ez = az - bz;
    float px = ax + bx, py = ay + by, pz = az + bz;
    float dm = fmaf(ex, ex, fmaf(ey, ey, ez * ez));
    float dp = fmaf(px, px, fmaf(py, py, pz * pz));
    float nd = fminf(dm, dp);

    for (int off = 32; off > 0; off >>= 1) {
        dist += __shfl_down(dist, off, 64);
        nd   += __shfl_down(nd,   off, 64);
    }
    int wave = tid >> 6, lane = tid & 63;
    if (lane == 0) { fin[wave * 2] = dist; fin[wave * 2 + 1] = nd; }
    __syncthreads();
    if (tid == 0) {
        const float inv = 1.0f / 32768.0f;
        float a = (fin[0] + fin[2] + fin[4] + fin[6]) * inv;
        float c = (fin[1] + fin[3] + fin[5] + fin[7]) * inv;
        atomicAdd(&out[0], a);   // loss_xyz
        atomicAdd(&out[1], c);   // loss_normal
    }
}

extern "C" void kernel_launch(void* const* d_in, const int* in_sizes, int n_in,
                              void* d_out, int out_size, void* d_ws, size_t ws_size,
                              hipStream_t stream) {
    const float* xyz1 = (const float*)d_in[0];   // [8,4096,3]
    const float* xyz2 = (const float*)d_in[1];
    const float* nrm1 = (const float*)d_in[2];   // normal_rebuild
    const float* nrm2 = (const float*)d_in[3];   // normal_gt
    float* out = (float*)d_out;

    unsigned long long* res = (unsigned long long*)d_ws;   // 2 MB

    chamfer7_scan<<<GRID1, TPB, 0, stream>>>(xyz1, xyz2, res, out);
    chamfer7_finalize<<<NQTOT / 256, 256, 0, stream>>>(nrm1, nrm2, res, out);
}